// Round 4
// baseline (316.401 us; speedup 1.0000x reference)
//
#include <hip/hip_runtime.h>

// Problem constants (GATConv_17635135717523)
// N=50000 nodes, E=800000 edges, IN=256, H=8, O=32, H*O=256
#define N_NODES 50000
#define N_EDGES 800000
#define NPAD    50176   // 196*256
#define SPILL_CAP 8192
#define GEMM_BLOCKS 782
#define BUCKET_BLOCKS 1563   // 1563*512 = 800256 >= E

typedef __bf16 bf16x8 __attribute__((ext_vector_type(8)));
typedef float  fx4    __attribute__((ext_vector_type(4)));
typedef unsigned short us8 __attribute__((ext_vector_type(8)));

__device__ __forceinline__ float b2f(unsigned short u) {
    return __uint_as_float(((unsigned)u) << 16);
}
__device__ __forceinline__ unsigned short f2b(float f) {
    unsigned x = __float_as_uint(f);
    return (unsigned short)((x + 0x7FFFu + ((x >> 16) & 1u)) >> 16);
}

// ------------------------------------------------------- prep
// blocks 0..15:  coalesced W transpose via LDS 64x64 tiles -> Wt bf16 [n][k]
// blocks 16..31: M2t[j][k] fp32 (j<8 -> el col j, j>=8 -> er col j-8)
// blocks 32..227: zero cursor; block 32 zeroes spill_n
__global__ __launch_bounds__(256) void prep_w(
    const float* __restrict__ W,
    const float* __restrict__ attn_l, const float* __restrict__ attn_r,
    unsigned short* __restrict__ Wt, float* __restrict__ M2t,
    int* __restrict__ cursor, int* __restrict__ spill_n) {
    __shared__ float T[64 * 65];
    int b = blockIdx.x, t = threadIdx.x;
    if (b < 16) {
        int bi = b >> 2, bj = b & 3;          // k-tile, n-tile
        int r = t >> 2, cq = t & 3;           // k-local row, col quarter
        const float* wp = W + (size_t)(bi * 64 + r) * 256 + bj * 64 + cq * 16;
#pragma unroll
        for (int i = 0; i < 16; ++i) T[r * 65 + cq * 16 + i] = wp[i];
        __syncthreads();
        int n = t >> 2, ks = (t & 3) * 16;    // n-local, k-chunk
        us8 o0, o1;
#pragma unroll
        for (int i = 0; i < 8; ++i) o0[i] = f2b(T[(ks + i) * 65 + n]);
#pragma unroll
        for (int i = 0; i < 8; ++i) o1[i] = f2b(T[(ks + 8 + i) * 65 + n]);
        unsigned short* op = Wt + (size_t)(bj * 64 + n) * 256 + bi * 64 + ks;
        *reinterpret_cast<us8*>(op) = o0;
        *reinterpret_cast<us8*>(op + 8) = o1;
    } else if (b < 32) {
        int j = b - 16;
        const float* av = (j < 8) ? (attn_l + j * 32) : (attn_r + (j - 8) * 32);
        int c0 = (j & 7) * 32;
        float s = 0.f;
#pragma unroll
        for (int o = 0; o < 32; ++o) s += W[t * 256 + c0 + o] * av[o];
        M2t[j * 256 + t] = s;
    } else {
        cursor[(b - 32) * 256 + t] = 0;
        if (b == 32 && t == 0) *spill_n = 0;
    }
}

// ------------------------------------------------------- fused GEMM + bucket + el/er
// Heterogeneous grid, 512 threads/block:
//   blocks [0, GEMM_BLOCKS): ft = bf16(feat @ W) only. 64 rows x 256 cols,
//     8 waves x 32 cols, acc 4x2. No el/er side-path -> uniform waves,
//     ~-16 AGPR. Wt loads software-pipelined 1-deep; first-iter B loads
//     issued BEFORE staging (no dependency) so they ride under the feat
//     burst. setprio(1) around MFMAs (bucket waves co-resident = role
//     diversity, T5 regime).
//   blocks [GEMM_BLOCKS, +BUCKET_BLOCKS): per-block 512 edges bucketed
//     (atomic cursor + u16 scatter). Blocks bb < 782 additionally compute
//     el/er for a 64-row slab in pure fp32 (8 threads/row, shfl_xor
//     reduce) -- latency-idle blocks absorb the VALU work.
__global__ __launch_bounds__(512) void gemm_bucket(
    const float* __restrict__ feat,
    const unsigned short* __restrict__ Wt,
    const float* __restrict__ M2t,
    unsigned short* __restrict__ ft,
    float* __restrict__ el, float* __restrict__ er,
    const int* __restrict__ src, const int* __restrict__ dst,
    int* __restrict__ cursor, unsigned short* __restrict__ inedge,
    int* __restrict__ spill_n, int2* __restrict__ spill, int stride) {
    __shared__ unsigned short Alds[64 * 264];        // 33792 B (also bounce)
    const int tid = threadIdx.x;

    if (blockIdx.x >= GEMM_BLOCKS) {
        // ---------------- bucket + el/er part ----------------
        int bb = blockIdx.x - GEMM_BLOCKS;
        int t = bb * 512 + tid;
        if (t < N_EDGES) {
            int s = src[t], d = dst[t];
            int idx = atomicAdd(&cursor[d], 1);
            if (idx < stride) {
                inedge[(size_t)d * stride + idx] = (unsigned short)s;
            } else {
                int sp = atomicAdd(spill_n, 1);
                if (sp < SPILL_CAP) spill[sp] = make_int2(s, d);
            }
        }
        if (bb < GEMM_BLOCKS) {
            int row = bb * 64 + (tid >> 3);
            int p = tid & 7;
            if (row < N_NODES) {
                const float4* fr = reinterpret_cast<const float4*>(
                    feat + (size_t)row * 256 + p * 32);
                float4 x[8];
#pragma unroll
                for (int i = 0; i < 8; ++i) x[i] = fr[i];
                float pa[16];
#pragma unroll
                for (int jj = 0; jj < 16; ++jj) {
                    const float4* mp = reinterpret_cast<const float4*>(
                        M2t + jj * 256 + p * 32);
                    float s = 0.f;
#pragma unroll
                    for (int i = 0; i < 8; ++i) {
                        float4 m = mp[i];
                        s += x[i].x * m.x + x[i].y * m.y +
                             x[i].z * m.z + x[i].w * m.w;
                    }
                    pa[jj] = s;
                }
#pragma unroll
                for (int jj = 0; jj < 16; ++jj) {
                    pa[jj] += __shfl_xor(pa[jj], 1);
                    pa[jj] += __shfl_xor(pa[jj], 2);
                    pa[jj] += __shfl_xor(pa[jj], 4);
                }
                // static-index select (avoid runtime array index -> scratch)
                float outl = 0.f, outr = 0.f;
#pragma unroll
                for (int jj = 0; jj < 8; ++jj)
                    if (p == jj) { outl = pa[jj]; outr = pa[8 + jj]; }
                el[row * 8 + p] = outl;
                er[row * 8 + p] = outr;
            }
        }
        return;
    }

    // ---------------- gemm part ----------------
    const int lane = tid & 63;
    const int wid  = tid >> 6;                       // 0..7
    const int quad = lane >> 4, l15 = lane & 15;
    const int mbase = blockIdx.x * 64;
    const int nbase = wid * 32;

    // first-iteration B prefetch: independent of LDS, issue before staging
    const unsigned short* wb0 = Wt + (size_t)(nbase + l15) * 256 + quad * 8;
    const unsigned short* wb1 = wb0 + 16 * 256;
    bf16x8 bc0 = *reinterpret_cast<const bf16x8*>(wb0);
    bf16x8 bc1 = *reinterpret_cast<const bf16x8*>(wb1);

    fx4 acc[4][2];
#pragma unroll
    for (int i = 0; i < 4; ++i)
#pragma unroll
        for (int j = 0; j < 2; ++j) acc[i][j] = (fx4)0.0f;

    // ---- stage whole 64x256 tile: 8 threads per row, 128B each
    {
        const int srow = tid >> 3, s8 = tid & 7;
        int grow = mbase + srow;
        grow = grow < N_NODES ? grow : N_NODES - 1;
        const float* sp = feat + (size_t)grow * 256;
        unsigned short* sd = &Alds[srow * 264];
#pragma unroll
        for (int ii = 0; ii < 2; ++ii) {
            int c8 = ii * 16 + s8 * 2;               // 8-float group index
            float4 f0 = *reinterpret_cast<const float4*>(sp + c8 * 8);
            float4 f1 = *reinterpret_cast<const float4*>(sp + c8 * 8 + 4);
            float4 f2 = *reinterpret_cast<const float4*>(sp + c8 * 8 + 8);
            float4 f3 = *reinterpret_cast<const float4*>(sp + c8 * 8 + 12);
            us8 p0, p1;
            p0[0] = f2b(f0.x); p0[1] = f2b(f0.y); p0[2] = f2b(f0.z); p0[3] = f2b(f0.w);
            p0[4] = f2b(f1.x); p0[5] = f2b(f1.y); p0[6] = f2b(f1.z); p0[7] = f2b(f1.w);
            p1[0] = f2b(f2.x); p1[1] = f2b(f2.y); p1[2] = f2b(f2.z); p1[3] = f2b(f2.w);
            p1[4] = f2b(f3.x); p1[5] = f2b(f3.y); p1[6] = f2b(f3.z); p1[7] = f2b(f3.w);
            *reinterpret_cast<us8*>(sd + c8 * 8) = p0;
            *reinterpret_cast<us8*>(sd + c8 * 8 + 8) = p1;
        }
    }
    __syncthreads();

    // ---- K loop, barrier-free, B software-pipelined 1-deep
    for (int k0 = 0; k0 < 256; k0 += 32) {
        bf16x8 bn0 = bc0, bn1 = bc1;
        if (k0 < 224) {
            bn0 = *reinterpret_cast<const bf16x8*>(wb0 + k0 + 32);
            bn1 = *reinterpret_cast<const bf16x8*>(wb1 + k0 + 32);
        }
        const int krow = k0 + quad * 8;
        bf16x8 a[4];
#pragma unroll
        for (int mt = 0; mt < 4; ++mt)
            a[mt] = *reinterpret_cast<const bf16x8*>(&Alds[(mt * 16 + l15) * 264 + krow]);
        __builtin_amdgcn_s_setprio(1);
#pragma unroll
        for (int mt = 0; mt < 4; ++mt) {
            acc[mt][0] = __builtin_amdgcn_mfma_f32_16x16x32_bf16(a[mt], bc0, acc[mt][0], 0, 0, 0);
            acc[mt][1] = __builtin_amdgcn_mfma_f32_16x16x32_bf16(a[mt], bc1, acc[mt][1], 0, 0, 0);
        }
        __builtin_amdgcn_s_setprio(0);
        bc0 = bn0; bc1 = bn1;
    }
    __syncthreads();   // all waves done reading Alds -> reuse as bounce

    // ---- packed epilogue: per-wave LDS bounce -> us8 (16B) ft stores
    // C/D layout: col = lane&15, row = (lane>>4)*4 + reg  [verified m89/m91]
    unsigned short* bw = &Alds[wid * 512];   // 1KB per wave, wave-private
#pragma unroll
    for (int mt = 0; mt < 4; ++mt) {
#pragma unroll
        for (int r = 0; r < 4; ++r) {
            int rl = quad * 4 + r;
#pragma unroll
            for (int nt = 0; nt < 2; ++nt)
                bw[rl * 32 + nt * 16 + l15] = f2b(acc[mt][nt][r]);
        }
        // wave-internal ds ordering; compiler inserts lgkmcnt wait
        {
            int rl = lane >> 2;              // 0..15
            int c8 = lane & 3;               // 0..3 (8-short chunks)
            us8 v = *reinterpret_cast<const us8*>(&bw[rl * 32 + c8 * 8]);
            int grow = mbase + mt * 16 + rl;
            if (grow < N_NODES)
                *reinterpret_cast<us8*>(ft + (size_t)grow * 256 + nbase + c8 * 8) = v;
        }
    }
}

// ------------------------------------------------------- aggregation
// One wave per dst node, two waves per block. HALF-WAVE per edge: 32 lanes
// cover a 512B ft row at 16B/lane (us8); halves process edge pairs.
// Main loop: 16 edges per iter -- indices via TWO uint4 loads (u16 pairs,
// shift/mask extract; no runtime vector indexing), 8 ft gathers + 8 el
// loads in flight per lane. Softmax denom inline (|logit| ~ O(1)).
__global__ __launch_bounds__(128) void aggregate(
    const unsigned short* __restrict__ ft,
    const float* __restrict__ el, const float* __restrict__ er,
    const int* __restrict__ cursor,
    const unsigned short* __restrict__ inedge,
    const int* __restrict__ spill_n, const int2* __restrict__ spill,
    const float* __restrict__ bias,
    float* __restrict__ out, int stride) {
    int wid = threadIdx.x >> 6, lane = threadIdx.x & 63;
    int v = blockIdx.x * 2 + wid;          // grid exact: v < N always
    int deg_t = cursor[v];
    int deg = deg_t < stride ? deg_t : stride;   // bucketed edges
    int half = lane >> 5, l = lane & 31;
    int h = l >> 2;                         // head of elems [l*8, l*8+8)
    int sh = half * 16;
    float erv = er[v * 8 + h];
    const unsigned short* ip = inedge + (size_t)v * stride;
    const us8* ft8 = reinterpret_cast<const us8*>(ft);

    float a[8] = {0.f, 0.f, 0.f, 0.f, 0.f, 0.f, 0.f, 0.f};
    float s = 0.f;
    int j = 0;
    for (; j + 16 <= deg; j += 16) {        // 8 pairs = 16 edges per iter
        uint4 q0 = *reinterpret_cast<const uint4*>(ip + j);
        uint4 q1 = *reinterpret_cast<const uint4*>(ip + j + 8);
        int u[8];
        u[0] = (q0.x >> sh) & 0xffff; u[1] = (q0.y >> sh) & 0xffff;
        u[2] = (q0.z >> sh) & 0xffff; u[3] = (q0.w >> sh) & 0xffff;
        u[4] = (q1.x >> sh) & 0xffff; u[5] = (q1.y >> sh) & 0xffff;
        u[6] = (q1.z >> sh) & 0xffff; u[7] = (q1.w >> sh) & 0xffff;
        us8 f[8];
#pragma unroll
        for (int t = 0; t < 8; ++t) f[t] = ft8[(size_t)u[t] * 32 + l];
        float ee[8];
#pragma unroll
        for (int t = 0; t < 8; ++t) ee[t] = el[u[t] * 8 + h];
#pragma unroll
        for (int t = 0; t < 8; ++t) {
            float x = ee[t] + erv;
            x = x > 0.f ? x : 0.2f * x;
            float w = __expf(x);
            s += w;
#pragma unroll
            for (int i = 0; i < 8; ++i) a[i] += w * b2f(f[t][i]);
        }
    }
    for (; j + 8 <= deg; j += 8) {          // 4 pairs = 8 edges
        uint4 q0 = *reinterpret_cast<const uint4*>(ip + j);
        int u[4];
        u[0] = (q0.x >> sh) & 0xffff; u[1] = (q0.y >> sh) & 0xffff;
        u[2] = (q0.z >> sh) & 0xffff; u[3] = (q0.w >> sh) & 0xffff;
        us8 f[4];
#pragma unroll
        for (int t = 0; t < 4; ++t) f[t] = ft8[(size_t)u[t] * 32 + l];
#pragma unroll
        for (int t = 0; t < 4; ++t) {
            float x = el[u[t] * 8 + h] + erv;
            x = x > 0.f ? x : 0.2f * x;
            float w = __expf(x);
            s += w;
#pragma unroll
            for (int i = 0; i < 8; ++i) a[i] += w * b2f(f[t][i]);
        }
    }
    for (; j + 2 <= deg; j += 2) {          // pair tail
        int u = ip[j + half];
        us8 f = ft8[(size_t)u * 32 + l];
        float x = el[u * 8 + h] + erv;
        x = x > 0.f ? x : 0.2f * x;
        float w = __expf(x);
        s += w;
#pragma unroll
        for (int i = 0; i < 8; ++i) a[i] += w * b2f(f[i]);
    }
    if (j < deg && half == 0) {             // odd edge: half 0 only
        int u = ip[j];
        us8 f = ft8[(size_t)u * 32 + l];
        float x = el[u * 8 + h] + erv;
        x = x > 0.f ? x : 0.2f * x;
        float w = __expf(x);
        s += w;
#pragma unroll
        for (int i = 0; i < 8; ++i) a[i] += w * b2f(f[i]);
    }
    // spilled edges (expected never taken; correctness net for deg>stride)
    if (deg_t > stride) {
        int sn = *spill_n;
        if (sn > SPILL_CAP) sn = SPILL_CAP;
        for (int t = 0; t < sn; ++t) {
            int2 e = spill[t];
            if (e.y == v && half == 0) {
                int u = e.x;
                us8 f = ft8[(size_t)u * 32 + l];
                float x = el[u * 8 + h] + erv;
                x = x > 0.f ? x : 0.2f * x;
                float w = __expf(x);
                s += w;
#pragma unroll
                for (int i = 0; i < 8; ++i) a[i] += w * b2f(f[i]);
            }
        }
    }
    // combine halves (both halves end with full sums)
#pragma unroll
    for (int i = 0; i < 8; ++i) a[i] += __shfl_xor(a[i], 32);
    s += __shfl_xor(s, 32);
    float inv = deg_t > 0 ? 1.0f / s : 0.f;

    // write: lane stores 4 floats at float4-index l*2+half of the row
    int fi = l * 2 + half;
    float4 bb = reinterpret_cast<const float4*>(bias)[fi];
    int base = half * 4;
    float4 o;
    o.x = a[base + 0] * inv + bb.x;
    o.y = a[base + 1] * inv + bb.y;
    o.z = a[base + 2] * inv + bb.z;
    o.w = a[base + 3] * inv + bb.w;
    reinterpret_cast<float4*>(out)[(size_t)v * 64 + fi] = o;
}

// ------------------------------------------------------- launch (3 dispatches)
extern "C" void kernel_launch(void* const* d_in, const int* in_sizes, int n_in,
                              void* d_out, int out_size, void* d_ws, size_t ws_size,
                              hipStream_t stream) {
    const float* feat   = (const float*)d_in[0];
    const float* W      = (const float*)d_in[1];
    const float* attn_l = (const float*)d_in[2];
    const float* attn_r = (const float*)d_in[3];
    const float* bias   = (const float*)d_in[4];
    const int* src = (const int*)d_in[5];
    const int* dst = (const int*)d_in[6];
    float* out = (float*)d_out;

    char* ws = (char*)d_ws;
    // workspace layout (16B aligned)
    unsigned short* Wt     = (unsigned short*)(ws + 0);          //    131,072
    float* M2t             = (float*)(ws + 131072);              //     16,384
    unsigned short* ft     = (unsigned short*)(ws + 147456);     // 25,600,000
    float* el              = (float*)(ws + 25747456);            //  1,600,000
    float* er              = (float*)(ws + 27347456);            //  1,600,000
    int* cursor            = (int*)(ws + 28947456);              //    200,704
    int* spill_n           = (int*)(ws + 29148160);              //         64
    int2* spill            = (int2*)(ws + 29148224);             //     65,536
    unsigned short* inedge = (unsigned short*)(ws + 29213760);   // stride*2*NPAD

    // bucket stride: multiple of 8 (16B-aligned index rows for uint4 loads),
    // capped at 64. Poisson(16) degrees: P(deg>32) ~ 1e-4 -> a handful of
    // spilled edges worst-case; spill list keeps overflow exact regardless.
    size_t avail = ws_size > 29213760ull ? ws_size - 29213760ull : 0;
    int stride = (int)(avail / (2ull * NPAD));
    stride &= ~7;
    if (stride > 64) stride = 64;
    if (stride < 8) stride = 8;

    prep_w<<<228, 256, 0, stream>>>(W, attn_l, attn_r, Wt, M2t,
                                    cursor, spill_n);
    gemm_bucket<<<GEMM_BLOCKS + BUCKET_BLOCKS, 512, 0, stream>>>(
        feat, Wt, M2t, ft, el, er,
        src, dst, cursor, inedge, spill_n, spill, stride);
    aggregate<<<25000, 128, 0, stream>>>(ft, el, er, cursor, inedge,
                                         spill_n, spill, bias, out, stride);
}

// Round 5
// 236.474 us; speedup vs baseline: 1.3380x; 1.3380x over previous
//
#include <hip/hip_runtime.h>

// Problem constants (GATConv_17635135717523)
// N=50000 nodes, E=800000 edges, IN=256, H=8, O=32, H*O=256
#define N_NODES 50000
#define N_EDGES 800000
#define NPAD    50176   // 196*256
#define SPILL_CAP 8192
#define GEMM_BLOCKS 782
#define BUCKET_BLOCKS 1563   // 1563*512 = 800256 >= E

typedef __bf16 bf16x8 __attribute__((ext_vector_type(8)));
typedef float  fx4    __attribute__((ext_vector_type(4)));
typedef unsigned short us8 __attribute__((ext_vector_type(8)));

__device__ __forceinline__ float b2f(unsigned short u) {
    return __uint_as_float(((unsigned)u) << 16);
}
__device__ __forceinline__ unsigned short f2b(float f) {
    unsigned x = __float_as_uint(f);
    return (unsigned short)((x + 0x7FFFu + ((x >> 16) & 1u)) >> 16);
}

// ------------------------------------------------------- prep
// blocks 0..15: coalesced W transpose via LDS 64x64 tiles -> Wt bf16 [n][k]
// blocks 16..211: zero cursor; block 16 also zeroes spill_n
__global__ __launch_bounds__(256) void prep_w(
    const float* __restrict__ W,
    unsigned short* __restrict__ Wt,
    int* __restrict__ cursor, int* __restrict__ spill_n) {
    __shared__ float T[64 * 65];
    int b = blockIdx.x, t = threadIdx.x;
    if (b < 16) {
        int bi = b >> 2, bj = b & 3;          // k-tile, n-tile
        int r = t >> 2, cq = t & 3;           // k-local row, col quarter
        const float* wp = W + (size_t)(bi * 64 + r) * 256 + bj * 64 + cq * 16;
#pragma unroll
        for (int i = 0; i < 16; ++i) T[r * 65 + cq * 16 + i] = wp[i];
        __syncthreads();
        int n = t >> 2, ks = (t & 3) * 16;    // n-local, k-chunk
        us8 o0, o1;
#pragma unroll
        for (int i = 0; i < 8; ++i) o0[i] = f2b(T[(ks + i) * 65 + n]);
#pragma unroll
        for (int i = 0; i < 8; ++i) o1[i] = f2b(T[(ks + 8 + i) * 65 + n]);
        unsigned short* op = Wt + (size_t)(bj * 64 + n) * 256 + bi * 64 + ks;
        *reinterpret_cast<us8*>(op) = o0;
        *reinterpret_cast<us8*>(op + 8) = o1;
    } else {
        cursor[(b - 16) * 256 + t] = 0;
        if (b == 16 && t == 0) *spill_n = 0;
    }
}

// ------------------------------------------------------- fused GEMM + bucket
// Heterogeneous grid, 512 threads/block:
//   blocks [0, GEMM_BLOCKS): ft = bf16(feat @ W); el/er derived from the
//     fp32 accumulators via in-wave shfl reduction (wave w owns exactly
//     head w's 32 cols). 8 waves, acc 4x2, B 1-deep software pipeline.
//     LDS A-tile is [64][512B] with chunk swizzle c16 ^= (row&7): staging
//     writes, K-loop b128 reads, and the bounce are conflict-free(-ish).
//     Epilogue bounces acc through LDS and emits only FULL-LINE contiguous
//     stores (1KB/wave for ft, 2KB runs for el/er) to kill the ~2x HBM
//     write amplification seen in rounds 1-4 (WRITE 73MB vs 35 logical).
//   blocks [GEMM_BLOCKS, +BUCKET_BLOCKS): THIN edge bucketing (1 edge/thr,
//     atomic cursor + u16 scatter) -- fast-retiring backfill (round-4
//     lesson: never put serial work in the filler blocks).
__global__ __launch_bounds__(512) void gemm_bucket(
    const float* __restrict__ feat,
    const unsigned short* __restrict__ Wt,
    const float* __restrict__ attn_l, const float* __restrict__ attn_r,
    unsigned short* __restrict__ ft,
    float* __restrict__ el, float* __restrict__ er,
    const int* __restrict__ src, const int* __restrict__ dst,
    int* __restrict__ cursor, unsigned short* __restrict__ inedge,
    int* __restrict__ spill_n, int2* __restrict__ spill, int stride) {
    __shared__ unsigned short Alds[64 * 256];   // 32768 B, swizzled tile
    __shared__ float elds[2][64][8];            // 4096 B (el, er bounce)
    const int tid = threadIdx.x;

    if (blockIdx.x >= GEMM_BLOCKS) {
        // ---------------- thin bucket part ----------------
        int t = (blockIdx.x - GEMM_BLOCKS) * 512 + tid;
        if (t < N_EDGES) {
            int s = src[t], d = dst[t];
            int idx = atomicAdd(&cursor[d], 1);
            if (idx < stride) {
                inedge[(size_t)d * stride + idx] = (unsigned short)s;
            } else {
                int sp = atomicAdd(spill_n, 1);
                if (sp < SPILL_CAP) spill[sp] = make_int2(s, d);
            }
        }
        return;
    }

    // ---------------- gemm part ----------------
    const int lane = tid & 63;
    const int wid  = tid >> 6;                       // 0..7 == head
    const int quad = lane >> 4, l15 = lane & 15;
    const int mbase = blockIdx.x * 64;
    const int nbase = wid * 32;

    // first-iteration B prefetch (independent of LDS)
    const unsigned short* wb0 = Wt + (size_t)(nbase + l15) * 256 + quad * 8;
    const unsigned short* wb1 = wb0 + 16 * 256;
    bf16x8 bc0 = *reinterpret_cast<const bf16x8*>(wb0);
    bf16x8 bc1 = *reinterpret_cast<const bf16x8*>(wb1);

    // attention vectors for the el/er epilogue (tiny, L1/L2 resident)
    float al0 = attn_l[nbase + l15], al1 = attn_l[nbase + 16 + l15];
    float ar0 = attn_r[nbase + l15], ar1 = attn_r[nbase + 16 + l15];

    fx4 acc[4][2];
#pragma unroll
    for (int i = 0; i < 4; ++i)
#pragma unroll
        for (int j = 0; j < 2; ++j) acc[i][j] = (fx4)0.0f;

    // ---- stage 64x256 tile: 8 thr/row, 32B contiguous per (thread,ii),
    // chunk c16 stored at slot c16^(row&7) -> octet-conflict-free writes
    {
        const int srow = tid >> 3, s8 = tid & 7;
        int grow = mbase + srow;
        grow = grow < N_NODES ? grow : N_NODES - 1;
        const float* sp = feat + (size_t)grow * 256;
        unsigned short* sd = Alds + srow * 256;
        const int r7 = srow & 7;
#pragma unroll
        for (int ii = 0; ii < 4; ++ii) {
            int c16 = ii * 8 + s8;
            float4 f0 = *reinterpret_cast<const float4*>(sp + c16 * 8);
            float4 f1 = *reinterpret_cast<const float4*>(sp + c16 * 8 + 4);
            us8 p;
            p[0] = f2b(f0.x); p[1] = f2b(f0.y); p[2] = f2b(f0.z); p[3] = f2b(f0.w);
            p[4] = f2b(f1.x); p[5] = f2b(f1.y); p[6] = f2b(f1.z); p[7] = f2b(f1.w);
            *reinterpret_cast<us8*>(sd + (c16 ^ r7) * 8) = p;
        }
    }
    __syncthreads();

    // ---- K loop, barrier-free, B software-pipelined 1-deep
    for (int k0 = 0; k0 < 256; k0 += 32) {
        bf16x8 bn0 = bc0, bn1 = bc1;
        if (k0 < 224) {
            bn0 = *reinterpret_cast<const bf16x8*>(wb0 + k0 + 32);
            bn1 = *reinterpret_cast<const bf16x8*>(wb1 + k0 + 32);
        }
        const int c16 = (k0 >> 3) + quad;
        bf16x8 a[4];
#pragma unroll
        for (int mt = 0; mt < 4; ++mt) {
            int row = mt * 16 + l15;
            a[mt] = *reinterpret_cast<const bf16x8*>(
                Alds + row * 256 + ((c16 ^ (row & 7)) * 8));
        }
#pragma unroll
        for (int mt = 0; mt < 4; ++mt) {
            acc[mt][0] = __builtin_amdgcn_mfma_f32_16x16x32_bf16(a[mt], bc0, acc[mt][0], 0, 0, 0);
            acc[mt][1] = __builtin_amdgcn_mfma_f32_16x16x32_bf16(a[mt], bc1, acc[mt][1], 0, 0, 0);
        }
        bc0 = bn0; bc1 = bn1;
    }
    __syncthreads();   // all reads done -> reuse Alds as ft bounce

    // ---- bounce acc -> swizzled LDS tile (bf16) + el/er shfl-reduce
    // C/D layout: col = lane&15, row = (lane>>4)*4 + reg  [verified m89/m91]
#pragma unroll
    for (int mt = 0; mt < 4; ++mt) {
#pragma unroll
        for (int r = 0; r < 4; ++r) {
            int row = mt * 16 + quad * 4 + r;
            int r7 = row & 7;
#pragma unroll
            for (int nt = 0; nt < 2; ++nt) {
                int c16 = (nbase >> 3) + nt * 2 + (l15 >> 3);
                Alds[row * 256 + ((c16 ^ r7) * 8) + (l15 & 7)] = f2b(acc[mt][nt][r]);
            }
            // el/er partial for this row: this lane covers cols l15, l15+16
            float cl = acc[mt][0][r] * al0 + acc[mt][1][r] * al1;
            float cr = acc[mt][0][r] * ar0 + acc[mt][1][r] * ar1;
#pragma unroll
            for (int m = 1; m < 16; m <<= 1) {
                cl += __shfl_xor(cl, m);
                cr += __shfl_xor(cr, m);
            }
            if (l15 == 0)      elds[0][row][wid] = cl;
            else if (l15 == 1) elds[1][row][wid] = cr;
        }
    }
    __syncthreads();

    // ---- coalesced global writes: full-line contiguous runs only
    // ft: per instr, wave covers 2 full rows = 1KB contiguous
#pragma unroll
    for (int i = 0; i < 4; ++i) {
        int g = i * 512 + tid;               // tile chunk index 0..2047
        int row = g >> 5, c16 = g & 31;
        us8 v = *reinterpret_cast<const us8*>(
            Alds + row * 256 + ((c16 ^ (row & 7)) * 8));
        if (mbase + row < N_NODES)
            *reinterpret_cast<us8*>(ft + (size_t)(mbase + row) * 256 + c16 * 8) = v;
    }
    // el/er: 2KB contiguous runs (threads 0..127 el, 128..255 er)
    if (tid < 256) {
        int sel = tid >> 7, t = tid & 127;
        int row = t >> 1;
        float4 v = *reinterpret_cast<const float4*>(&elds[sel][0][0] + t * 4);
        float* dstp = sel ? er : el;
        if (mbase + row < N_NODES)
            *reinterpret_cast<float4*>(dstp + (size_t)(mbase + row) * 8 + (t & 1) * 4) = v;
    }
}

// ------------------------------------------------------- aggregation
// (proven round-3 version, 69 us) One wave per dst node, two waves per
// block. HALF-WAVE per edge: 32 lanes cover a 512B ft row at 16B/lane
// (us8); halves process edge pairs; cross-half combine via shfl_xor(32).
// Softmax denom accumulated inline (no max-subtraction; |logit| ~ O(1)).
__global__ __launch_bounds__(128) void aggregate(
    const unsigned short* __restrict__ ft,
    const float* __restrict__ el, const float* __restrict__ er,
    const int* __restrict__ cursor,
    const unsigned short* __restrict__ inedge,
    const int* __restrict__ spill_n, const int2* __restrict__ spill,
    const float* __restrict__ bias,
    float* __restrict__ out, int stride) {
    int wid = threadIdx.x >> 6, lane = threadIdx.x & 63;
    int v = blockIdx.x * 2 + wid;          // grid exact: v < N always
    int deg_t = cursor[v];
    int deg = deg_t < stride ? deg_t : stride;   // bucketed edges
    int half = lane >> 5, l = lane & 31;
    int h = l >> 2;                         // head of elems [l*8, l*8+8)
    float erv = er[v * 8 + h];
    const unsigned short* ip = inedge + (size_t)v * stride;
    const us8* ft8 = reinterpret_cast<const us8*>(ft);

    float a[8] = {0.f, 0.f, 0.f, 0.f, 0.f, 0.f, 0.f, 0.f};
    float s = 0.f;
    int j = 0;
    for (; j + 8 <= deg; j += 8) {          // 4 pairs = 8 edges per iter
        int u[4];
#pragma unroll
        for (int t = 0; t < 4; ++t) u[t] = ip[j + 2 * t + half];
        us8 f[4];
#pragma unroll
        for (int t = 0; t < 4; ++t) f[t] = ft8[(size_t)u[t] * 32 + l];
#pragma unroll
        for (int t = 0; t < 4; ++t) {
            float x = el[u[t] * 8 + h] + erv;
            x = x > 0.f ? x : 0.2f * x;
            float w = __expf(x);
            s += w;
#pragma unroll
            for (int i = 0; i < 8; ++i) a[i] += w * b2f(f[t][i]);
        }
    }
    for (; j + 2 <= deg; j += 2) {          // pair tail
        int u = ip[j + half];
        us8 f = ft8[(size_t)u * 32 + l];
        float x = el[u * 8 + h] + erv;
        x = x > 0.f ? x : 0.2f * x;
        float w = __expf(x);
        s += w;
#pragma unroll
        for (int i = 0; i < 8; ++i) a[i] += w * b2f(f[i]);
    }
    if (j < deg && half == 0) {             // odd edge: half 0 only
        int u = ip[j];
        us8 f = ft8[(size_t)u * 32 + l];
        float x = el[u * 8 + h] + erv;
        x = x > 0.f ? x : 0.2f * x;
        float w = __expf(x);
        s += w;
#pragma unroll
        for (int i = 0; i < 8; ++i) a[i] += w * b2f(f[i]);
    }
    // spilled edges (expected never taken; correctness net for deg>stride)
    if (deg_t > stride) {
        int sn = *spill_n;
        if (sn > SPILL_CAP) sn = SPILL_CAP;
        for (int t = 0; t < sn; ++t) {
            int2 e = spill[t];
            if (e.y == v && half == 0) {
                int u = e.x;
                us8 f = ft8[(size_t)u * 32 + l];
                float x = el[u * 8 + h] + erv;
                x = x > 0.f ? x : 0.2f * x;
                float w = __expf(x);
                s += w;
#pragma unroll
                for (int i = 0; i < 8; ++i) a[i] += w * b2f(f[i]);
            }
        }
    }
    // combine halves (both halves end with full sums)
#pragma unroll
    for (int i = 0; i < 8; ++i) a[i] += __shfl_xor(a[i], 32);
    s += __shfl_xor(s, 32);
    float inv = deg_t > 0 ? 1.0f / s : 0.f;

    // write: lane stores 4 floats at float4-index l*2+half of the row
    int fi = l * 2 + half;
    float4 bb = reinterpret_cast<const float4*>(bias)[fi];
    int base = half * 4;
    float4 o;
    o.x = a[base + 0] * inv + bb.x;
    o.y = a[base + 1] * inv + bb.y;
    o.z = a[base + 2] * inv + bb.z;
    o.w = a[base + 3] * inv + bb.w;
    reinterpret_cast<float4*>(out)[(size_t)v * 64 + fi] = o;
}

// ------------------------------------------------------- launch (3 dispatches)
extern "C" void kernel_launch(void* const* d_in, const int* in_sizes, int n_in,
                              void* d_out, int out_size, void* d_ws, size_t ws_size,
                              hipStream_t stream) {
    const float* feat   = (const float*)d_in[0];
    const float* W      = (const float*)d_in[1];
    const float* attn_l = (const float*)d_in[2];
    const float* attn_r = (const float*)d_in[3];
    const float* bias   = (const float*)d_in[4];
    const int* src = (const int*)d_in[5];
    const int* dst = (const int*)d_in[6];
    float* out = (float*)d_out;

    char* ws = (char*)d_ws;
    // workspace layout (16B aligned)
    unsigned short* Wt     = (unsigned short*)(ws + 0);          //    131,072
    unsigned short* ft     = (unsigned short*)(ws + 147456);     // 25,600,000
    float* el              = (float*)(ws + 25747456);            //  1,600,000
    float* er              = (float*)(ws + 27347456);            //  1,600,000
    int* cursor            = (int*)(ws + 28947456);              //    200,704
    int* spill_n           = (int*)(ws + 29148160);              //         64
    int2* spill            = (int2*)(ws + 29148224);             //     65,536
    unsigned short* inedge = (unsigned short*)(ws + 29213760);   // stride*2*NPAD

    // bucket stride: as many u16 slots per node as workspace allows, cap 64.
    // Poisson(16) degrees (max ~38 this dataset); spill keeps overflow exact.
    size_t avail = ws_size > 29213760ull ? ws_size - 29213760ull : 0;
    int stride = (int)(avail / (2ull * NPAD));
    if (stride > 64) stride = 64;

    prep_w<<<212, 256, 0, stream>>>(W, Wt, cursor, spill_n);
    gemm_bucket<<<GEMM_BLOCKS + BUCKET_BLOCKS, 512, 0, stream>>>(
        feat, Wt, attn_l, attn_r, ft, el, er,
        src, dst, cursor, inedge, spill_n, spill, stride);
    aggregate<<<25000, 128, 0, stream>>>(ft, el, er, cursor, inedge,
                                         spill_n, spill, bias, out, stride);
}

// Round 6
// 235.843 us; speedup vs baseline: 1.3416x; 1.0027x over previous
//
#include <hip/hip_runtime.h>

// Problem constants (GATConv_17635135717523)
// N=50000 nodes, E=800000 edges, IN=256, H=8, O=32, H*O=256
#define N_NODES 50000
#define N_EDGES 800000
#define NPAD    50176   // 196*256
#define SPILL_CAP 8192
#define GEMM_BLOCKS 782
#define BUCKET_BLOCKS 1563   // 1563*512 = 800256 >= E

typedef __bf16 bf16x8 __attribute__((ext_vector_type(8)));
typedef float  fx4    __attribute__((ext_vector_type(4)));
typedef unsigned short us8 __attribute__((ext_vector_type(8)));

__device__ __forceinline__ float b2f(unsigned short u) {
    return __uint_as_float(((unsigned)u) << 16);
}
__device__ __forceinline__ unsigned short f2b(float f) {
    unsigned x = __float_as_uint(f);
    return (unsigned short)((x + 0x7FFFu + ((x >> 16) & 1u)) >> 16);
}

// ------------------------------------------------------- prep
// blocks 0..15: coalesced W transpose via LDS 64x64 tiles -> Wt bf16 [n][k]
// blocks 16..211: zero cursor; block 16 also zeroes spill_n
__global__ __launch_bounds__(256) void prep_w(
    const float* __restrict__ W,
    unsigned short* __restrict__ Wt,
    int* __restrict__ cursor, int* __restrict__ spill_n) {
    __shared__ float T[64 * 65];
    int b = blockIdx.x, t = threadIdx.x;
    if (b < 16) {
        int bi = b >> 2, bj = b & 3;          // k-tile, n-tile
        int r = t >> 2, cq = t & 3;           // k-local row, col quarter
        const float* wp = W + (size_t)(bi * 64 + r) * 256 + bj * 64 + cq * 16;
#pragma unroll
        for (int i = 0; i < 16; ++i) T[r * 65 + cq * 16 + i] = wp[i];
        __syncthreads();
        int n = t >> 2, ks = (t & 3) * 16;    // n-local, k-chunk
        us8 o0, o1;
#pragma unroll
        for (int i = 0; i < 8; ++i) o0[i] = f2b(T[(ks + i) * 65 + n]);
#pragma unroll
        for (int i = 0; i < 8; ++i) o1[i] = f2b(T[(ks + 8 + i) * 65 + n]);
        unsigned short* op = Wt + (size_t)(bj * 64 + n) * 256 + bi * 64 + ks;
        *reinterpret_cast<us8*>(op) = o0;
        *reinterpret_cast<us8*>(op + 8) = o1;
    } else {
        cursor[(b - 16) * 256 + t] = 0;
        if (b == 16 && t == 0) *spill_n = 0;
    }
}

// ------------------------------------------------------- fused GEMM + bucket
// Heterogeneous grid, 512 threads/block:
//   blocks [0, GEMM_BLOCKS): ft = bf16(feat @ W). Proven round-3 structure
//     (264-stride LDS tile, 2 barriers, per-wave 1KB bounce epilogue), plus:
//     - el/er derived from acc: wave w owns head w's 32 cols exactly, so
//       el[row,w] = sum_l15(acc . attn_l) -- 4-step shfl over l15, scalar
//       store from lanes l15==0/1. No M2 side path, no wave-0 straggler,
//       no extra barrier.
//     - B (Wt) loads software-pipelined 1-deep; first iter's B issued
//       before staging (independent of LDS).
//     - setprio(1) around the MFMA cluster (bucket waves co-resident
//       give the CU scheduler role diversity -- T5 regime).
//   blocks [GEMM_BLOCKS, +BUCKET_BLOCKS): THIN edge bucketing (1 edge/thr,
//     atomic cursor + u16 scatter) -- fast-retiring backfill (round-4
//     lesson: never put serial work in the filler blocks).
__global__ __launch_bounds__(512) void gemm_bucket(
    const float* __restrict__ feat,
    const unsigned short* __restrict__ Wt,
    const float* __restrict__ attn_l, const float* __restrict__ attn_r,
    unsigned short* __restrict__ ft,
    float* __restrict__ el, float* __restrict__ er,
    const int* __restrict__ src, const int* __restrict__ dst,
    int* __restrict__ cursor, unsigned short* __restrict__ inedge,
    int* __restrict__ spill_n, int2* __restrict__ spill, int stride) {
    __shared__ unsigned short Alds[64 * 264];        // 33792 B (also bounce)
    const int tid = threadIdx.x;

    if (blockIdx.x >= GEMM_BLOCKS) {
        // ---------------- thin bucket part ----------------
        int t = (blockIdx.x - GEMM_BLOCKS) * 512 + tid;
        if (t < N_EDGES) {
            int s = src[t], d = dst[t];
            int idx = atomicAdd(&cursor[d], 1);
            if (idx < stride) {
                inedge[(size_t)d * stride + idx] = (unsigned short)s;
            } else {
                int sp = atomicAdd(spill_n, 1);
                if (sp < SPILL_CAP) spill[sp] = make_int2(s, d);
            }
        }
        return;
    }

    // ---------------- gemm part ----------------
    const int lane = tid & 63;
    const int wid  = tid >> 6;                       // 0..7 == head
    const int quad = lane >> 4, l15 = lane & 15;
    const int mbase = blockIdx.x * 64;
    const int nbase = wid * 32;

    // first-iteration B prefetch (independent of LDS)
    const unsigned short* wb0 = Wt + (size_t)(nbase + l15) * 256 + quad * 8;
    const unsigned short* wb1 = wb0 + 16 * 256;
    bf16x8 bc0 = *reinterpret_cast<const bf16x8*>(wb0);
    bf16x8 bc1 = *reinterpret_cast<const bf16x8*>(wb1);

    // attention weights for this wave's head (cols nbase+l15, nbase+16+l15)
    float al0 = attn_l[nbase + l15], al1 = attn_l[nbase + 16 + l15];
    float ar0 = attn_r[nbase + l15], ar1 = attn_r[nbase + 16 + l15];

    fx4 acc[4][2];
#pragma unroll
    for (int i = 0; i < 4; ++i)
#pragma unroll
        for (int j = 0; j < 2; ++j) acc[i][j] = (fx4)0.0f;

    // ---- stage whole 64x256 tile: 8 threads per row, 128B each
    {
        const int srow = tid >> 3, s8 = tid & 7;
        int grow = mbase + srow;
        grow = grow < N_NODES ? grow : N_NODES - 1;
        const float* sp = feat + (size_t)grow * 256;
        unsigned short* sd = &Alds[srow * 264];
#pragma unroll
        for (int ii = 0; ii < 2; ++ii) {
            int c8 = ii * 16 + s8 * 2;               // 8-float group index
            float4 f0 = *reinterpret_cast<const float4*>(sp + c8 * 8);
            float4 f1 = *reinterpret_cast<const float4*>(sp + c8 * 8 + 4);
            float4 f2 = *reinterpret_cast<const float4*>(sp + c8 * 8 + 8);
            float4 f3 = *reinterpret_cast<const float4*>(sp + c8 * 8 + 12);
            us8 p0, p1;
            p0[0] = f2b(f0.x); p0[1] = f2b(f0.y); p0[2] = f2b(f0.z); p0[3] = f2b(f0.w);
            p0[4] = f2b(f1.x); p0[5] = f2b(f1.y); p0[6] = f2b(f1.z); p0[7] = f2b(f1.w);
            p1[0] = f2b(f2.x); p1[1] = f2b(f2.y); p1[2] = f2b(f2.z); p1[3] = f2b(f2.w);
            p1[4] = f2b(f3.x); p1[5] = f2b(f3.y); p1[6] = f2b(f3.z); p1[7] = f2b(f3.w);
            *reinterpret_cast<us8*>(sd + c8 * 8) = p0;
            *reinterpret_cast<us8*>(sd + c8 * 8 + 8) = p1;
        }
    }
    __syncthreads();

    // ---- K loop, barrier-free, B software-pipelined 1-deep
    for (int k0 = 0; k0 < 256; k0 += 32) {
        bf16x8 bn0 = bc0, bn1 = bc1;
        if (k0 < 224) {
            bn0 = *reinterpret_cast<const bf16x8*>(wb0 + k0 + 32);
            bn1 = *reinterpret_cast<const bf16x8*>(wb1 + k0 + 32);
        }
        const int krow = k0 + quad * 8;
        bf16x8 a[4];
#pragma unroll
        for (int mt = 0; mt < 4; ++mt)
            a[mt] = *reinterpret_cast<const bf16x8*>(&Alds[(mt * 16 + l15) * 264 + krow]);
        __builtin_amdgcn_s_setprio(1);
#pragma unroll
        for (int mt = 0; mt < 4; ++mt) {
            acc[mt][0] = __builtin_amdgcn_mfma_f32_16x16x32_bf16(a[mt], bc0, acc[mt][0], 0, 0, 0);
            acc[mt][1] = __builtin_amdgcn_mfma_f32_16x16x32_bf16(a[mt], bc1, acc[mt][1], 0, 0, 0);
        }
        __builtin_amdgcn_s_setprio(0);
        bc0 = bn0; bc1 = bn1;
    }

    // ---- el/er from acc: in-wave reduce over l15 (wave w == head w).
    // C/D layout: col = lane&15, row = (lane>>4)*4 + reg  [verified m89/m91]
    // Scalar stores issue early and drain under the LDS bounce below.
#pragma unroll
    for (int mt = 0; mt < 4; ++mt) {
#pragma unroll
        for (int r = 0; r < 4; ++r) {
            int row = mbase + mt * 16 + quad * 4 + r;
            float cl = acc[mt][0][r] * al0 + acc[mt][1][r] * al1;
            float cr = acc[mt][0][r] * ar0 + acc[mt][1][r] * ar1;
#pragma unroll
            for (int m = 1; m < 16; m <<= 1) {
                cl += __shfl_xor(cl, m);
                cr += __shfl_xor(cr, m);
            }
            if (row < N_NODES) {
                if (l15 == 0)      el[row * 8 + wid] = cl;
                else if (l15 == 1) er[row * 8 + wid] = cr;
            }
        }
    }
    __syncthreads();   // all waves done reading Alds -> reuse as bounce

    // ---- packed epilogue: per-wave LDS bounce -> us8 (16B) ft stores
    unsigned short* bw = &Alds[wid * 512];   // 1KB per wave, wave-private
#pragma unroll
    for (int mt = 0; mt < 4; ++mt) {
#pragma unroll
        for (int r = 0; r < 4; ++r) {
            int rl = quad * 4 + r;
#pragma unroll
            for (int nt = 0; nt < 2; ++nt)
                bw[rl * 32 + nt * 16 + l15] = f2b(acc[mt][nt][r]);
        }
        // wave-internal ds ordering; compiler inserts lgkmcnt wait
        {
            int rl = lane >> 2;              // 0..15
            int c8 = lane & 3;               // 0..3 (8-short chunks)
            us8 v = *reinterpret_cast<const us8*>(&bw[rl * 32 + c8 * 8]);
            int grow = mbase + mt * 16 + rl;
            if (grow < N_NODES)
                *reinterpret_cast<us8*>(ft + (size_t)grow * 256 + nbase + c8 * 8) = v;
        }
    }
}

// ------------------------------------------------------- aggregation
// Proven round-2 shape (4 waves / 256 threads, 69.0us) with ONE change:
// 16-edge batches via two uint4 index loads -> 8 ft-row gathers in flight
// per lane (2x MLP vs round-2's 4). One wave per dst node; HALF-WAVE per
// edge: 32 lanes cover a 512B ft row at 16B/lane (us8); halves process
// edge pairs (j, j+1); cross-half combine via shfl_xor(32).
// Softmax denom accumulated inline (no max-subtraction; |logit| ~ O(1)).
__global__ __launch_bounds__(256) void aggregate(
    const unsigned short* __restrict__ ft,
    const float* __restrict__ el, const float* __restrict__ er,
    const int* __restrict__ cursor,
    const unsigned short* __restrict__ inedge,
    const int* __restrict__ spill_n, const int2* __restrict__ spill,
    const float* __restrict__ bias,
    float* __restrict__ out, int stride) {
    int wid = threadIdx.x >> 6, lane = threadIdx.x & 63;
    int v = blockIdx.x * 4 + wid;          // grid exact: v < N always
    int deg_t = cursor[v];
    int deg = deg_t < stride ? deg_t : stride;   // bucketed edges
    int half = lane >> 5, l = lane & 31;
    int h = l >> 2;                         // head of elems [l*8, l*8+8)
    int sh = half * 16;
    float erv = er[v * 8 + h];
    const unsigned short* ip = inedge + (size_t)v * stride;
    const us8* ft8 = reinterpret_cast<const us8*>(ft);

    float a[8] = {0.f, 0.f, 0.f, 0.f, 0.f, 0.f, 0.f, 0.f};
    float s = 0.f;
    int j = 0;
    for (; j + 16 <= deg; j += 16) {        // 8 pairs = 16 edges per iter
        uint4 q0 = *reinterpret_cast<const uint4*>(ip + j);
        uint4 q1 = *reinterpret_cast<const uint4*>(ip + j + 8);
        int u[8];
        u[0] = (q0.x >> sh) & 0xffff; u[1] = (q0.y >> sh) & 0xffff;
        u[2] = (q0.z >> sh) & 0xffff; u[3] = (q0.w >> sh) & 0xffff;
        u[4] = (q1.x >> sh) & 0xffff; u[5] = (q1.y >> sh) & 0xffff;
        u[6] = (q1.z >> sh) & 0xffff; u[7] = (q1.w >> sh) & 0xffff;
        us8 f[8];
#pragma unroll
        for (int t = 0; t < 8; ++t) f[t] = ft8[(size_t)u[t] * 32 + l];
        float ee[8];
#pragma unroll
        for (int t = 0; t < 8; ++t) ee[t] = el[u[t] * 8 + h];
#pragma unroll
        for (int t = 0; t < 8; ++t) {
            float x = ee[t] + erv;
            x = x > 0.f ? x : 0.2f * x;
            float w = __expf(x);
            s += w;
#pragma unroll
            for (int i = 0; i < 8; ++i) a[i] += w * b2f(f[t][i]);
        }
    }
    for (; j + 8 <= deg; j += 8) {          // 4 pairs = 8 edges
        uint4 q0 = *reinterpret_cast<const uint4*>(ip + j);
        int u[4];
        u[0] = (q0.x >> sh) & 0xffff; u[1] = (q0.y >> sh) & 0xffff;
        u[2] = (q0.z >> sh) & 0xffff; u[3] = (q0.w >> sh) & 0xffff;
        us8 f[4];
#pragma unroll
        for (int t = 0; t < 4; ++t) f[t] = ft8[(size_t)u[t] * 32 + l];
#pragma unroll
        for (int t = 0; t < 4; ++t) {
            float x = el[u[t] * 8 + h] + erv;
            x = x > 0.f ? x : 0.2f * x;
            float w = __expf(x);
            s += w;
#pragma unroll
            for (int i = 0; i < 8; ++i) a[i] += w * b2f(f[t][i]);
        }
    }
    for (; j + 2 <= deg; j += 2) {          // pair tail
        int u = ip[j + half];
        us8 f = ft8[(size_t)u * 32 + l];
        float x = el[u * 8 + h] + erv;
        x = x > 0.f ? x : 0.2f * x;
        float w = __expf(x);
        s += w;
#pragma unroll
        for (int i = 0; i < 8; ++i) a[i] += w * b2f(f[i]);
    }
    if (j < deg && half == 0) {             // odd edge: half 0 only
        int u = ip[j];
        us8 f = ft8[(size_t)u * 32 + l];
        float x = el[u * 8 + h] + erv;
        x = x > 0.f ? x : 0.2f * x;
        float w = __expf(x);
        s += w;
#pragma unroll
        for (int i = 0; i < 8; ++i) a[i] += w * b2f(f[i]);
    }
    // spilled edges (expected never taken; correctness net for deg>stride)
    if (deg_t > stride) {
        int sn = *spill_n;
        if (sn > SPILL_CAP) sn = SPILL_CAP;
        for (int t = 0; t < sn; ++t) {
            int2 e = spill[t];
            if (e.y == v && half == 0) {
                int u = e.x;
                us8 f = ft8[(size_t)u * 32 + l];
                float x = el[u * 8 + h] + erv;
                x = x > 0.f ? x : 0.2f * x;
                float w = __expf(x);
                s += w;
#pragma unroll
                for (int i = 0; i < 8; ++i) a[i] += w * b2f(f[i]);
            }
        }
    }
    // combine halves (both halves end with full sums)
#pragma unroll
    for (int i = 0; i < 8; ++i) a[i] += __shfl_xor(a[i], 32);
    s += __shfl_xor(s, 32);
    float inv = deg_t > 0 ? 1.0f / s : 0.f;

    // write: lane stores 4 floats at float4-index l*2+half of the row
    int fi = l * 2 + half;
    float4 bb = reinterpret_cast<const float4*>(bias)[fi];
    int base = half * 4;
    float4 o;
    o.x = a[base + 0] * inv + bb.x;
    o.y = a[base + 1] * inv + bb.y;
    o.z = a[base + 2] * inv + bb.z;
    o.w = a[base + 3] * inv + bb.w;
    reinterpret_cast<float4*>(out)[(size_t)v * 64 + fi] = o;
}

// ------------------------------------------------------- launch (3 dispatches)
extern "C" void kernel_launch(void* const* d_in, const int* in_sizes, int n_in,
                              void* d_out, int out_size, void* d_ws, size_t ws_size,
                              hipStream_t stream) {
    const float* feat   = (const float*)d_in[0];
    const float* W      = (const float*)d_in[1];
    const float* attn_l = (const float*)d_in[2];
    const float* attn_r = (const float*)d_in[3];
    const float* bias   = (const float*)d_in[4];
    const int* src = (const int*)d_in[5];
    const int* dst = (const int*)d_in[6];
    float* out = (float*)d_out;

    char* ws = (char*)d_ws;
    // workspace layout (16B aligned)
    unsigned short* Wt     = (unsigned short*)(ws + 0);          //    131,072
    unsigned short* ft     = (unsigned short*)(ws + 147456);     // 25,600,000
    float* el              = (float*)(ws + 25747456);            //  1,600,000
    float* er              = (float*)(ws + 27347456);            //  1,600,000
    int* cursor            = (int*)(ws + 28947456);              //    200,704
    int* spill_n           = (int*)(ws + 29148160);              //         64
    int2* spill            = (int2*)(ws + 29148224);             //     65,536
    unsigned short* inedge = (unsigned short*)(ws + 29213760);   // stride*2*NPAD

    // bucket stride: multiple of 8 (16B-aligned rows for uint4 index loads),
    // cap 64. Poisson(16) degrees (max ~38 this dataset); spill list keeps
    // any overflow exact regardless.
    size_t avail = ws_size > 29213760ull ? ws_size - 29213760ull : 0;
    int stride = (int)(avail / (2ull * NPAD));
    stride &= ~7;
    if (stride > 64) stride = 64;
    if (stride < 8) stride = 8;

    prep_w<<<212, 256, 0, stream>>>(W, Wt, cursor, spill_n);
    gemm_bucket<<<GEMM_BLOCKS + BUCKET_BLOCKS, 512, 0, stream>>>(
        feat, Wt, attn_l, attn_r, ft, el, er,
        src, dst, cursor, inedge, spill_n, spill, stride);
    aggregate<<<12500, 256, 0, stream>>>(ft, el, er, cursor, inedge,
                                         spill_n, spill, bias, out, stride);
}

// Round 7
// 226.116 us; speedup vs baseline: 1.3993x; 1.0430x over previous
//
#include <hip/hip_runtime.h>

// Problem constants (GATConv_17635135717523)
// N=50000 nodes, E=800000 edges, IN=256, H=8, O=32, H*O=256
#define N_NODES 50000
#define N_EDGES 800000
#define NPAD    50176   // 196*256
#define SPILL_CAP 8192
#define GEMM_BLOCKS 782
#define BUCKET_BLOCKS 391    // 391*512 threads * 4 edges = 800768 >= E

typedef __bf16 bf16x8 __attribute__((ext_vector_type(8)));
typedef float  fx4    __attribute__((ext_vector_type(4)));
typedef unsigned short us8 __attribute__((ext_vector_type(8)));

__device__ __forceinline__ float b2f(unsigned short u) {
    return __uint_as_float(((unsigned)u) << 16);
}
__device__ __forceinline__ unsigned short f2b(float f) {
    unsigned x = __float_as_uint(f);
    return (unsigned short)((x + 0x7FFFu + ((x >> 16) & 1u)) >> 16);
}

// ------------------------------------------------------- prep
// blocks 0..15:  coalesced W transpose via LDS 64x64 tiles -> Wt bf16 [n][k]
// blocks 16..31: M2t[j][k] hi/lo bf16 (j<8 -> el head j, j>=8 -> er head j-8)
// blocks 32..227: zero cursor; block 32 also zeroes spill_n
__global__ __launch_bounds__(256) void prep_w(
    const float* __restrict__ W,
    const float* __restrict__ attn_l, const float* __restrict__ attn_r,
    unsigned short* __restrict__ Wt,
    unsigned short* __restrict__ M2t_hi, unsigned short* __restrict__ M2t_lo,
    int* __restrict__ cursor, int* __restrict__ spill_n) {
    __shared__ float T[64 * 65];
    int b = blockIdx.x, t = threadIdx.x;
    if (b < 16) {
        int bi = b >> 2, bj = b & 3;          // k-tile, n-tile
        int r = t >> 2, cq = t & 3;           // k-local row, col quarter
        const float* wp = W + (size_t)(bi * 64 + r) * 256 + bj * 64 + cq * 16;
#pragma unroll
        for (int i = 0; i < 16; ++i) T[r * 65 + cq * 16 + i] = wp[i];
        __syncthreads();
        int n = t >> 2, ks = (t & 3) * 16;    // n-local, k-chunk
        us8 o0, o1;
#pragma unroll
        for (int i = 0; i < 8; ++i) o0[i] = f2b(T[(ks + i) * 65 + n]);
#pragma unroll
        for (int i = 0; i < 8; ++i) o1[i] = f2b(T[(ks + 8 + i) * 65 + n]);
        unsigned short* op = Wt + (size_t)(bj * 64 + n) * 256 + bi * 64 + ks;
        *reinterpret_cast<us8*>(op) = o0;
        *reinterpret_cast<us8*>(op + 8) = o1;
    } else if (b < 32) {
        int j = b - 16;
        const float* av = (j < 8) ? (attn_l + j * 32) : (attn_r + (j - 8) * 32);
        int c0 = (j & 7) * 32;
        float s = 0.f;
#pragma unroll
        for (int o = 0; o < 32; ++o) s += W[t * 256 + c0 + o] * av[o];
        unsigned short h = f2b(s);
        M2t_hi[j * 256 + t] = h;
        M2t_lo[j * 256 + t] = f2b(s - b2f(h));
    } else {
        cursor[(b - 32) * 256 + t] = 0;
        if (b == 32 && t == 0) *spill_n = 0;
    }
}

// ------------------------------------------------------- fused GEMM + bucket
// Heterogeneous grid, 512 threads/block.
//   blocks [0, GEMM_BLOCKS): ft = bf16(feat @ W) -- EXACT round-3 structure
//     (proven 80us merged: 264-stride LDS tile, in-loop B loads, 2 barriers,
//     per-wave 1KB bounce epilogue; no prefetch/setprio/shfl-heavy epilogue,
//     which regressed rounds 5-6). One balanced change: the M2 (el/er) side
//     path moves from wave 0 (which carried hi+lo = 2 MFMAs + 2 global loads
//     per K-iter, the block-latency straggler) to waves 1 and 2, each with
//     ONE combined B-fragment: cols 0-7 = M2_hi, cols 8-15 = M2_lo of its
//     target (el for wave 1, er for wave 2). hi+lo summed post-hoc with a
//     single shfl_xor(8). All waves hold identical A fragments, so any wave
//     can do this.
//   blocks [GEMM_BLOCKS, +BUCKET_BLOCKS): bucketing at 4 edges/thread
//     (int4 loads, r1's proven pattern): bucket blocks inherit this
//     kernel's 33KB LDS allocation (4 blocks/CU cap), so 4 independent
//     atomic chains per thread restores atomic-level parallelism.
__global__ __launch_bounds__(512) void gemm_bucket(
    const float* __restrict__ feat,
    const unsigned short* __restrict__ Wt,
    const unsigned short* __restrict__ M2t_hi,
    const unsigned short* __restrict__ M2t_lo,
    unsigned short* __restrict__ ft,
    float* __restrict__ el, float* __restrict__ er,
    const int* __restrict__ src, const int* __restrict__ dst,
    int* __restrict__ cursor, unsigned short* __restrict__ inedge,
    int* __restrict__ spill_n, int2* __restrict__ spill, int stride) {
    __shared__ unsigned short Alds[64 * 264];        // 33792 B (also bounce)
    const int tid = threadIdx.x;

    if (blockIdx.x >= GEMM_BLOCKS) {
        // ---------------- bucket part: 4 edges per thread ----------------
        int t = (blockIdx.x - GEMM_BLOCKS) * 512 + tid;
        if (t < N_EDGES / 4) {
            int4 s4 = reinterpret_cast<const int4*>(src)[t];
            int4 d4 = reinterpret_cast<const int4*>(dst)[t];
            int ss[4] = {s4.x, s4.y, s4.z, s4.w};
            int dd[4] = {d4.x, d4.y, d4.z, d4.w};
#pragma unroll
            for (int i = 0; i < 4; ++i) {
                int idx = atomicAdd(&cursor[dd[i]], 1);
                if (idx < stride) {
                    inedge[(size_t)dd[i] * stride + idx] = (unsigned short)ss[i];
                } else {
                    int sp = atomicAdd(spill_n, 1);
                    if (sp < SPILL_CAP) spill[sp] = make_int2(ss[i], dd[i]);
                }
            }
        }
        return;
    }

    // ---------------- gemm part ----------------
    const int lane = tid & 63;
    const int wid  = tid >> 6;                       // 0..7
    const int quad = lane >> 4, l15 = lane & 15;
    const int mbase = blockIdx.x * 64;
    const int nbase = wid * 32;

    // M2 combined-fragment base for waves 1 (el) and 2 (er):
    // col l15 in [0,8) -> hi rows, [8,16) -> lo rows; row j = head (l15&7),
    // offset +8 for er.
    const unsigned short* m2base = nullptr;
    if (wid == 1 || wid == 2) {
        int jrow = ((wid == 2) ? 8 : 0) + (l15 & 7);
        m2base = ((l15 < 8) ? M2t_hi : M2t_lo) + jrow * 256;
    }

    fx4 acc[4][2];
    fx4 acce[4];
#pragma unroll
    for (int i = 0; i < 4; ++i) {
        acce[i] = (fx4)0.0f;
#pragma unroll
        for (int j = 0; j < 2; ++j) acc[i][j] = (fx4)0.0f;
    }

    // ---- stage whole 64x256 tile: 8 threads per row, 128B each
    {
        const int srow = tid >> 3, s8 = tid & 7;
        int grow = mbase + srow;
        grow = grow < N_NODES ? grow : N_NODES - 1;
        const float* sp = feat + (size_t)grow * 256;
        unsigned short* sd = &Alds[srow * 264];
#pragma unroll
        for (int ii = 0; ii < 2; ++ii) {
            int c8 = ii * 16 + s8 * 2;               // 8-float group index
            float4 f0 = *reinterpret_cast<const float4*>(sp + c8 * 8);
            float4 f1 = *reinterpret_cast<const float4*>(sp + c8 * 8 + 4);
            float4 f2 = *reinterpret_cast<const float4*>(sp + c8 * 8 + 8);
            float4 f3 = *reinterpret_cast<const float4*>(sp + c8 * 8 + 12);
            us8 p0, p1;
            p0[0] = f2b(f0.x); p0[1] = f2b(f0.y); p0[2] = f2b(f0.z); p0[3] = f2b(f0.w);
            p0[4] = f2b(f1.x); p0[5] = f2b(f1.y); p0[6] = f2b(f1.z); p0[7] = f2b(f1.w);
            p1[0] = f2b(f2.x); p1[1] = f2b(f2.y); p1[2] = f2b(f2.z); p1[3] = f2b(f2.w);
            p1[4] = f2b(f3.x); p1[5] = f2b(f3.y); p1[6] = f2b(f3.z); p1[7] = f2b(f3.w);
            *reinterpret_cast<us8*>(sd + c8 * 8) = p0;
            *reinterpret_cast<us8*>(sd + c8 * 8 + 8) = p1;
        }
    }
    __syncthreads();

    // ---- K loop, barrier-free (r3 form: B loaded in-loop, no pipeline)
    for (int k0 = 0; k0 < 256; k0 += 32) {
        const int krow = k0 + quad * 8;
        bf16x8 a[4], b[2];
#pragma unroll
        for (int mt = 0; mt < 4; ++mt)
            a[mt] = *reinterpret_cast<const bf16x8*>(&Alds[(mt * 16 + l15) * 264 + krow]);
#pragma unroll
        for (int nt = 0; nt < 2; ++nt)
            b[nt] = *reinterpret_cast<const bf16x8*>(Wt + (nbase + nt * 16 + l15) * 256 + krow);
#pragma unroll
        for (int mt = 0; mt < 4; ++mt)
#pragma unroll
            for (int nt = 0; nt < 2; ++nt)
                acc[mt][nt] = __builtin_amdgcn_mfma_f32_16x16x32_bf16(
                    a[mt], b[nt], acc[mt][nt], 0, 0, 0);
        if (wid == 1 || wid == 2) {
            bf16x8 bm = *reinterpret_cast<const bf16x8*>(m2base + krow);
#pragma unroll
            for (int mt = 0; mt < 4; ++mt)
                acce[mt] = __builtin_amdgcn_mfma_f32_16x16x32_bf16(a[mt], bm, acce[mt], 0, 0, 0);
        }
    }

    // ---- el/er epilogue (waves 1,2 only): combine hi (lanes 0-7) + lo
    // (lanes 8-15) with one shfl_xor(8), store from lanes l15<8.
    // C/D layout: col = lane&15, row = (lane>>4)*4 + reg  [verified m89/m91]
    if (wid == 1 || wid == 2) {
        float* dstp = (wid == 1) ? el : er;
#pragma unroll
        for (int mt = 0; mt < 4; ++mt) {
#pragma unroll
            for (int r = 0; r < 4; ++r) {
                int row = mbase + mt * 16 + quad * 4 + r;
                float c = acce[mt][r];
                c += __shfl_xor(c, 8);
                if (row < N_NODES && l15 < 8)
                    dstp[row * 8 + l15] = c;
            }
        }
    }
    __syncthreads();   // all waves done reading Alds -> reuse as bounce

    // ---- packed epilogue: per-wave LDS bounce -> us8 (16B) ft stores
    unsigned short* bw = &Alds[wid * 512];   // 1KB per wave, wave-private
#pragma unroll
    for (int mt = 0; mt < 4; ++mt) {
#pragma unroll
        for (int r = 0; r < 4; ++r) {
            int rl = quad * 4 + r;
#pragma unroll
            for (int nt = 0; nt < 2; ++nt)
                bw[rl * 32 + nt * 16 + l15] = f2b(acc[mt][nt][r]);
        }
        // wave-internal ds ordering; compiler inserts lgkmcnt wait
        {
            int rl = lane >> 2;              // 0..15
            int c8 = lane & 3;               // 0..3 (8-short chunks)
            us8 v = *reinterpret_cast<const us8*>(&bw[rl * 32 + c8 * 8]);
            int grow = mbase + mt * 16 + rl;
            if (grow < N_NODES)
                *reinterpret_cast<us8*>(ft + (size_t)grow * 256 + nbase + c8 * 8) = v;
        }
    }
}

// ------------------------------------------------------- aggregation
// (round-6 version, ~69us) One wave per dst node, 4 waves per block.
// 16-edge batches via two uint4 index loads -> 8 ft-row gathers in flight
// per lane. HALF-WAVE per edge: 32 lanes cover a 512B ft row at 16B/lane
// (us8); halves process edge pairs; cross-half combine via shfl_xor(32).
// Softmax denom accumulated inline (no max-subtraction; |logit| ~ O(1)).
__global__ __launch_bounds__(256) void aggregate(
    const unsigned short* __restrict__ ft,
    const float* __restrict__ el, const float* __restrict__ er,
    const int* __restrict__ cursor,
    const unsigned short* __restrict__ inedge,
    const int* __restrict__ spill_n, const int2* __restrict__ spill,
    const float* __restrict__ bias,
    float* __restrict__ out, int stride) {
    int wid = threadIdx.x >> 6, lane = threadIdx.x & 63;
    int v = blockIdx.x * 4 + wid;          // grid exact: v < N always
    int deg_t = cursor[v];
    int deg = deg_t < stride ? deg_t : stride;   // bucketed edges
    int half = lane >> 5, l = lane & 31;
    int h = l >> 2;                         // head of elems [l*8, l*8+8)
    int sh = half * 16;
    float erv = er[v * 8 + h];
    const unsigned short* ip = inedge + (size_t)v * stride;
    const us8* ft8 = reinterpret_cast<const us8*>(ft);

    float a[8] = {0.f, 0.f, 0.f, 0.f, 0.f, 0.f, 0.f, 0.f};
    float s = 0.f;
    int j = 0;
    for (; j + 16 <= deg; j += 16) {        // 8 pairs = 16 edges per iter
        uint4 q0 = *reinterpret_cast<const uint4*>(ip + j);
        uint4 q1 = *reinterpret_cast<const uint4*>(ip + j + 8);
        int u[8];
        u[0] = (q0.x >> sh) & 0xffff; u[1] = (q0.y >> sh) & 0xffff;
        u[2] = (q0.z >> sh) & 0xffff; u[3] = (q0.w >> sh) & 0xffff;
        u[4] = (q1.x >> sh) & 0xffff; u[5] = (q1.y >> sh) & 0xffff;
        u[6] = (q1.z >> sh) & 0xffff; u[7] = (q1.w >> sh) & 0xffff;
        us8 f[8];
#pragma unroll
        for (int t = 0; t < 8; ++t) f[t] = ft8[(size_t)u[t] * 32 + l];
        float ee[8];
#pragma unroll
        for (int t = 0; t < 8; ++t) ee[t] = el[u[t] * 8 + h];
#pragma unroll
        for (int t = 0; t < 8; ++t) {
            float x = ee[t] + erv;
            x = x > 0.f ? x : 0.2f * x;
            float w = __expf(x);
            s += w;
#pragma unroll
            for (int i = 0; i < 8; ++i) a[i] += w * b2f(f[t][i]);
        }
    }
    for (; j + 8 <= deg; j += 8) {          // 4 pairs = 8 edges
        uint4 q0 = *reinterpret_cast<const uint4*>(ip + j);
        int u[4];
        u[0] = (q0.x >> sh) & 0xffff; u[1] = (q0.y >> sh) & 0xffff;
        u[2] = (q0.z >> sh) & 0xffff; u[3] = (q0.w >> sh) & 0xffff;
        us8 f[4];
#pragma unroll
        for (int t = 0; t < 4; ++t) f[t] = ft8[(size_t)u[t] * 32 + l];
#pragma unroll
        for (int t = 0; t < 4; ++t) {
            float x = el[u[t] * 8 + h] + erv;
            x = x > 0.f ? x : 0.2f * x;
            float w = __expf(x);
            s += w;
#pragma unroll
            for (int i = 0; i < 8; ++i) a[i] += w * b2f(f[t][i]);
        }
    }
    for (; j + 2 <= deg; j += 2) {          // pair tail
        int u = ip[j + half];
        us8 f = ft8[(size_t)u * 32 + l];
        float x = el[u * 8 + h] + erv;
        x = x > 0.f ? x : 0.2f * x;
        float w = __expf(x);
        s += w;
#pragma unroll
        for (int i = 0; i < 8; ++i) a[i] += w * b2f(f[i]);
    }
    if (j < deg && half == 0) {             // odd edge: half 0 only
        int u = ip[j];
        us8 f = ft8[(size_t)u * 32 + l];
        float x = el[u * 8 + h] + erv;
        x = x > 0.f ? x : 0.2f * x;
        float w = __expf(x);
        s += w;
#pragma unroll
        for (int i = 0; i < 8; ++i) a[i] += w * b2f(f[i]);
    }
    // spilled edges (expected never taken; correctness net for deg>stride)
    if (deg_t > stride) {
        int sn = *spill_n;
        if (sn > SPILL_CAP) sn = SPILL_CAP;
        for (int t = 0; t < sn; ++t) {
            int2 e = spill[t];
            if (e.y == v && half == 0) {
                int u = e.x;
                us8 f = ft8[(size_t)u * 32 + l];
                float x = el[u * 8 + h] + erv;
                x = x > 0.f ? x : 0.2f * x;
                float w = __expf(x);
                s += w;
#pragma unroll
                for (int i = 0; i < 8; ++i) a[i] += w * b2f(f[i]);
            }
        }
    }
    // combine halves (both halves end with full sums)
#pragma unroll
    for (int i = 0; i < 8; ++i) a[i] += __shfl_xor(a[i], 32);
    s += __shfl_xor(s, 32);
    float inv = deg_t > 0 ? 1.0f / s : 0.f;

    // write: lane stores 4 floats at float4-index l*2+half of the row
    int fi = l * 2 + half;
    float4 bb = reinterpret_cast<const float4*>(bias)[fi];
    int base = half * 4;
    float4 o;
    o.x = a[base + 0] * inv + bb.x;
    o.y = a[base + 1] * inv + bb.y;
    o.z = a[base + 2] * inv + bb.z;
    o.w = a[base + 3] * inv + bb.w;
    reinterpret_cast<float4*>(out)[(size_t)v * 64 + fi] = o;
}

// ------------------------------------------------------- launch (3 dispatches)
extern "C" void kernel_launch(void* const* d_in, const int* in_sizes, int n_in,
                              void* d_out, int out_size, void* d_ws, size_t ws_size,
                              hipStream_t stream) {
    const float* feat   = (const float*)d_in[0];
    const float* W      = (const float*)d_in[1];
    const float* attn_l = (const float*)d_in[2];
    const float* attn_r = (const float*)d_in[3];
    const float* bias   = (const float*)d_in[4];
    const int* src = (const int*)d_in[5];
    const int* dst = (const int*)d_in[6];
    float* out = (float*)d_out;

    char* ws = (char*)d_ws;
    // workspace layout (16B aligned)
    unsigned short* Wt     = (unsigned short*)(ws + 0);          //    131,072
    unsigned short* M2t_hi = (unsigned short*)(ws + 131072);     //      8,192
    unsigned short* M2t_lo = (unsigned short*)(ws + 139264);     //      8,192
    unsigned short* ft     = (unsigned short*)(ws + 147456);     // 25,600,000
    float* el              = (float*)(ws + 25747456);            //  1,600,000
    float* er              = (float*)(ws + 27347456);            //  1,600,000
    int* cursor            = (int*)(ws + 28947456);              //    200,704
    int* spill_n           = (int*)(ws + 29148160);              //         64
    int2* spill            = (int2*)(ws + 29148224);             //     65,536
    unsigned short* inedge = (unsigned short*)(ws + 29213760);   // stride*2*NPAD

    // bucket stride: multiple of 8 (16B-aligned rows for uint4 index loads),
    // cap 64. Poisson(16) degrees (max ~38 this dataset); spill list keeps
    // any overflow exact regardless.
    size_t avail = ws_size > 29213760ull ? ws_size - 29213760ull : 0;
    int stride = (int)(avail / (2ull * NPAD));
    stride &= ~7;
    if (stride > 64) stride = 64;
    if (stride < 8) stride = 8;

    prep_w<<<228, 256, 0, stream>>>(W, attn_l, attn_r, Wt, M2t_hi, M2t_lo,
                                    cursor, spill_n);
    gemm_bucket<<<GEMM_BLOCKS + BUCKET_BLOCKS, 512, 0, stream>>>(
        feat, Wt, M2t_hi, M2t_lo, ft, el, er,
        src, dst, cursor, inedge, spill_n, spill, stride);
    aggregate<<<12500, 256, 0, stream>>>(ft, el, er, cursor, inedge,
                                         spill_n, spill, bias, out, stride);
}